// Round 1
// baseline (1934.100 us; speedup 1.0000x reference)
//
#include <hip/hip_runtime.h>
#include <math.h>

#define BB 128
#define NN 4096
#define CC 768
#define HH 768
#define NCLS 1000
#define KK 16

// ---------------- Kernel 1: top-16 of r per batch ----------------
// 128 blocks x 256 threads. Thread t holds r[t + 256*i], i<16.
// 16 rounds of block argmax (tie -> smaller index), winner masked out.
__global__ __launch_bounds__(256) void topk_kernel(const float* __restrict__ r,
                                                   int* __restrict__ idx_out) {
    const int b = blockIdx.x;
    const int t = threadIdx.x;
    const float* rb = r + (size_t)b * NN;
    float v[16];
#pragma unroll
    for (int i = 0; i < 16; ++i) v[i] = rb[t + 256 * i];
    unsigned taken = 0;
    __shared__ float sval[256];
    __shared__ int   sidx[256];
    __shared__ int   swin;
    for (int round = 0; round < KK; ++round) {
        float best = -INFINITY; int bi = 0;
#pragma unroll
        for (int i = 0; i < 16; ++i) {
            if (!((taken >> i) & 1u) && v[i] > best) { best = v[i]; bi = i; }
        }
        sval[t] = best;
        sidx[t] = t + 256 * bi;
        __syncthreads();
        for (int off = 128; off > 0; off >>= 1) {
            if (t < off) {
                float ov = sval[t + off]; int oi = sidx[t + off];
                if (ov > sval[t] || (ov == sval[t] && oi < sidx[t])) {
                    sval[t] = ov; sidx[t] = oi;
                }
            }
            __syncthreads();
        }
        if (t == 0) { swin = sidx[0]; idx_out[b * KK + round] = sidx[0]; }
        __syncthreads();
        const int win = swin;
        if ((win & 255) == t) taken |= 1u << (win >> 8);
        __syncthreads();
    }
}

// ---------------- Kernel 2: h = tanh(x_topk @ W + b), score = h.v + vb ----
// Grid (128, 2): block handles batch b, 8 of its 16 k-rows (W reuse x8).
// 256 threads; thread t owns output columns j = t, t+256, t+512.
__global__ __launch_bounds__(256) void hscore_kernel(const float* __restrict__ x,
                                                     const int* __restrict__ idx,
                                                     const float* __restrict__ Ww,
                                                     const float* __restrict__ Wb,
                                                     const float* __restrict__ vw,
                                                     const float* __restrict__ vb,
                                                     float* __restrict__ score_out) {
    const int b    = blockIdx.x;
    const int half = blockIdx.y;
    const int t    = threadIdx.x;
    __shared__ float xs[8][CC];      // 24 KB
    __shared__ float red[8][256];    // 8 KB

    for (int k = 0; k < 8; ++k) {
        const int row = idx[b * KK + half * 8 + k];
        const float* xr = x + ((size_t)b * NN + row) * CC;
        for (int c = t; c < CC; c += 256) xs[k][c] = xr[c];
    }
    __syncthreads();

    float acc[8][3];
#pragma unroll
    for (int k = 0; k < 8; ++k) { acc[k][0] = 0.f; acc[k][1] = 0.f; acc[k][2] = 0.f; }

#pragma unroll 4
    for (int c = 0; c < CC; ++c) {
        const float w0 = Ww[(size_t)c * HH + t];
        const float w1 = Ww[(size_t)c * HH + t + 256];
        const float w2 = Ww[(size_t)c * HH + t + 512];
#pragma unroll
        for (int k = 0; k < 8; ++k) {
            const float xv = xs[k][c];
            acc[k][0] = fmaf(xv, w0, acc[k][0]);
            acc[k][1] = fmaf(xv, w1, acc[k][1]);
            acc[k][2] = fmaf(xv, w2, acc[k][2]);
        }
    }

    const float b0 = Wb[t], b1 = Wb[t + 256], b2 = Wb[t + 512];
    const float v0 = vw[t], v1 = vw[t + 256], v2 = vw[t + 512];
#pragma unroll
    for (int k = 0; k < 8; ++k) {
        red[k][t] = tanhf(acc[k][0] + b0) * v0
                  + tanhf(acc[k][1] + b1) * v1
                  + tanhf(acc[k][2] + b2) * v2;
    }
    __syncthreads();
    for (int off = 128; off > 0; off >>= 1) {
        if (t < off) {
#pragma unroll
            for (int k = 0; k < 8; ++k) red[k][t] += red[k][t + off];
        }
        __syncthreads();
    }
    if (t < 8) score_out[b * KK + half * 8 + t] = red[t][0] + vb[0];
}

// ---------------- Kernel 3: alpha = softmax(score), z = sum alpha*x_topk ---
__global__ __launch_bounds__(256) void softz_kernel(const float* __restrict__ x,
                                                    const int* __restrict__ idx,
                                                    const float* __restrict__ score,
                                                    float* __restrict__ z_out) {
    const int b = blockIdx.x;
    const int t = threadIdx.x;
    __shared__ float alpha[KK];
    if (t == 0) {
        float m = -INFINITY;
        for (int k = 0; k < KK; ++k) m = fmaxf(m, score[b * KK + k]);
        float s = 0.f;
        float e[KK];
        for (int k = 0; k < KK; ++k) { e[k] = expf(score[b * KK + k] - m); s += e[k]; }
        const float inv = 1.f / s;
        for (int k = 0; k < KK; ++k) alpha[k] = e[k] * inv;
    }
    __syncthreads();
    float z0 = 0.f, z1 = 0.f, z2 = 0.f;
    for (int k = 0; k < KK; ++k) {
        const int row = idx[b * KK + k];
        const float* xr = x + ((size_t)b * NN + row) * CC;
        const float a = alpha[k];
        z0 = fmaf(a, xr[t], z0);
        z1 = fmaf(a, xr[t + 256], z1);
        z2 = fmaf(a, xr[t + 512], z2);
    }
    z_out[(size_t)b * CC + t]       = z0;
    z_out[(size_t)b * CC + t + 256] = z1;
    z_out[(size_t)b * CC + t + 512] = z2;
}

// ---------------- Kernel 4: logits = z @ fc_w + fc_b ----------------------
// Grid (32 batch-groups of 4, 8 class-slices of 125). 128 threads.
__global__ __launch_bounds__(128) void logits_kernel(const float* __restrict__ z,
                                                     const float* __restrict__ fcw,
                                                     const float* __restrict__ fcb,
                                                     float* __restrict__ out) {
    const int bg = blockIdx.x;  // 0..31
    const int cs = blockIdx.y;  // 0..7
    const int t  = threadIdx.x; // 0..127
    __shared__ float zs[4][CC]; // 12 KB
    for (int i = t; i < 4 * CC; i += 128) zs[i / CC][i % CC] = z[(size_t)(bg * 4 + i / CC) * CC + (i % CC)];
    __syncthreads();
    if (t < 125) {
        const int j = cs * 125 + t;
        float a0 = fcb[j], a1 = a0, a2 = a0, a3 = a0;
#pragma unroll 4
        for (int c = 0; c < CC; ++c) {
            const float w = fcw[(size_t)c * NCLS + j];
            a0 = fmaf(zs[0][c], w, a0);
            a1 = fmaf(zs[1][c], w, a1);
            a2 = fmaf(zs[2][c], w, a2);
            a3 = fmaf(zs[3][c], w, a3);
        }
        out[(size_t)(bg * 4 + 0) * NCLS + j] = a0;
        out[(size_t)(bg * 4 + 1) * NCLS + j] = a1;
        out[(size_t)(bg * 4 + 2) * NCLS + j] = a2;
        out[(size_t)(bg * 4 + 3) * NCLS + j] = a3;
    }
}

extern "C" void kernel_launch(void* const* d_in, const int* in_sizes, int n_in,
                              void* d_out, int out_size, void* d_ws, size_t ws_size,
                              hipStream_t stream) {
    const float* x   = (const float*)d_in[0];
    const float* r   = (const float*)d_in[1];
    const float* Ww  = (const float*)d_in[2];
    const float* Wb  = (const float*)d_in[3];
    const float* vw  = (const float*)d_in[4];
    const float* vb  = (const float*)d_in[5];
    const float* fcw = (const float*)d_in[6];
    const float* fcb = (const float*)d_in[7];
    float* out = (float*)d_out;

    // workspace layout
    int*   idx   = (int*)d_ws;                          // 2048 ints   (8 KB)
    float* score = (float*)((char*)d_ws + 8192);        // 2048 floats (8 KB)
    float* z     = (float*)((char*)d_ws + 16384);       // 128*768 floats (384 KB)

    topk_kernel<<<BB, 256, 0, stream>>>(r, idx);
    hscore_kernel<<<dim3(BB, 2), 256, 0, stream>>>(x, idx, Ww, Wb, vw, vb, score);
    softz_kernel<<<BB, 256, 0, stream>>>(x, idx, score, z);
    logits_kernel<<<dim3(32, 8), 128, 0, stream>>>(z, fcw, fcb, out);
}